// Round 2
// baseline (1292.328 us; speedup 1.0000x reference)
//
#include <hip/hip_runtime.h>
#include <hip/hip_bf16.h>

// MultiHeadAttention: B=8, L=1024, D=1024, H=16, dh=64.
// ALL inputs fp32, output fp32 (threshold = exactly 2% of max|ref| => no bf16
// floor => _any_bf16 False). Internally: bf16 MFMA GEMMs (fp32->bf16 convert
// fused into LDS staging), scalar fp32 attention, fp32 LayerNorm.
//
// Pipeline (6 launches):
//  1-3) Q/K/V = X @ W^T + b   (MFMA 128x128 tile, fp32 in -> bf16 out to ws)
//  4)   attention per head-slab g (raw-reshape: slab g = contiguous [1024,64]
//       at flat offset g*65536; mask row = g % B; unnormalized exp, exact ref)
//  5)   O = ctx @ Wo^T + bo   (bf16 A, fp32 W -> fp32 out, overlays q/k slabs)
//  6)   LayerNorm(query + O) * gamma + beta -> d_out (fp32)
// ws: 64 MB.

typedef __bf16 bf16x8 __attribute__((ext_vector_type(8)));
typedef float  f32x4  __attribute__((ext_vector_type(4)));

#define MM 8192
#define NN 1024
#define KK 1024

__device__ __forceinline__ float2 bfpair(const __bf16* p) {
  unsigned u = *(const unsigned*)p;
  return make_float2(__uint_as_float(u << 16), __uint_as_float(u & 0xffff0000u));
}

union BfPack4 { __bf16 h[4]; uint2 u; };

// C[m,n] = sum_k A[m,k]*W[n,k] + bias[n].  W always fp32 [1024,1024] row-major.
// A fp32 or bf16 (A_BF16). Both staged into LDS as bf16, MFMA 16x16x32.
template<bool A_BF16, bool OUT_F32>
__global__ __launch_bounds__(256) void gemm_bias(
    const void* __restrict__ Ap, const float* __restrict__ W,
    const float* __restrict__ bias, void* __restrict__ Cout)
{
  __shared__ alignas(16) __bf16 As[128 * 40];  // stride 40 (80B, 8B-multiple)
  __shared__ alignas(16) __bf16 Bs[128 * 40];
  const int tid = threadIdx.x;
  const int l   = tid & 63;
  const int w   = tid >> 6;
  const int wm  = (w & 1) * 64;    // wave quadrant of the 128x128 tile
  const int wn  = (w >> 1) * 64;
  const int m0  = blockIdx.x * 128;
  const int n0  = blockIdx.y * 128;
  const int lr  = l & 15;
  const int lq  = l >> 4;

  f32x4 acc[4][4] = {};

  for (int kk = 0; kk < KK; kk += 32) {
    __syncthreads();
    if (A_BF16) {
      const __bf16* A = (const __bf16*)Ap;
      #pragma unroll
      for (int c = tid; c < 512; c += 256) {   // 512 chunks of 8 bf16
        int row = c >> 2;
        int ko  = (c & 3) * 8;
        *(uint4*)&As[row * 40 + ko] = *(const uint4*)&A[(size_t)(m0 + row) * KK + kk + ko];
      }
    } else {
      const float* A = (const float*)Ap;
      #pragma unroll
      for (int c = tid; c < 1024; c += 256) {  // 1024 chunks of 4 fp32 -> 4 bf16
        int row = c >> 3;
        int ko  = (c & 7) * 4;
        float4 f = *(const float4*)&A[(size_t)(m0 + row) * KK + kk + ko];
        BfPack4 p;
        p.h[0] = (__bf16)f.x; p.h[1] = (__bf16)f.y;
        p.h[2] = (__bf16)f.z; p.h[3] = (__bf16)f.w;
        *(uint2*)&As[row * 40 + ko] = p.u;
      }
    }
    #pragma unroll
    for (int c = tid; c < 1024; c += 256) {    // W fp32 -> bf16
      int row = c >> 3;
      int ko  = (c & 7) * 4;
      float4 f = *(const float4*)&W[(size_t)(n0 + row) * KK + kk + ko];
      BfPack4 p;
      p.h[0] = (__bf16)f.x; p.h[1] = (__bf16)f.y;
      p.h[2] = (__bf16)f.z; p.h[3] = (__bf16)f.w;
      *(uint2*)&Bs[row * 40 + ko] = p.u;
    }
    __syncthreads();
    bf16x8 af[4], bf[4];
    #pragma unroll
    for (int t = 0; t < 4; ++t) {
      af[t] = *(const bf16x8*)&As[(wm + t * 16 + lr) * 40 + lq * 8];
      bf[t] = *(const bf16x8*)&Bs[(wn + t * 16 + lr) * 40 + lq * 8];
    }
    #pragma unroll
    for (int mt = 0; mt < 4; ++mt)
      #pragma unroll
      for (int nt = 0; nt < 4; ++nt)
        acc[mt][nt] = __builtin_amdgcn_mfma_f32_16x16x32_bf16(af[mt], bf[nt], acc[mt][nt], 0, 0, 0);
  }

  // C/D layout: col = lane&15, row = (lane>>4)*4 + i   [m89/m91 verified]
  #pragma unroll
  for (int mt = 0; mt < 4; ++mt)
    #pragma unroll
    for (int nt = 0; nt < 4; ++nt)
      #pragma unroll
      for (int i = 0; i < 4; ++i) {
        int gm = m0 + wm + mt * 16 + lq * 4 + i;
        int gn = n0 + wn + nt * 16 + lr;
        float v = acc[mt][nt][i] + bias[gn];
        if (OUT_F32) ((float*)Cout)[(size_t)gm * NN + gn] = v;
        else         ((__bf16*)Cout)[(size_t)gm * NN + gn] = (__bf16)v;
      }
}

// Scalar register-blocked attention (correctness baseline).
// Block = (q-tile of 64 rows, head-slab g). Thread (tq=tid&15, tk=tid>>4):
//   S phase: rows tq+16r (r<4) x cols tk*8+j (j<8), fp32 acc
//   PV phase: rows tq+16r x channels tk*4+c, P round-trips through LDS (bf16)
__global__ __launch_bounds__(256) void attn_kernel(
    const __bf16* __restrict__ qb, const __bf16* __restrict__ kb,
    const __bf16* __restrict__ vb, const float* __restrict__ qm,
    const float* __restrict__ km, __bf16* __restrict__ ctxb)
{
  const int g   = blockIdx.y;   // 0..127
  const int qt  = blockIdx.x;   // 0..15
  const int tid = threadIdx.x;
  const int tq  = tid & 15;
  const int tk  = tid >> 4;

  __shared__ alignas(16) __bf16 Qs[64 * 68];    // pad stride 68 (8B-multiple)
  __shared__ alignas(16) __bf16 Ks[128 * 64];   // broadcast reads, no pad
  __shared__ alignas(16) __bf16 Vs[128 * 64];
  __shared__ alignas(16) __bf16 Ps[64 * 136];   // stride 136 (16B-multiple)
  __shared__ float rsred[16][64];
  __shared__ float rowsum[64];

  const size_t gbase = (size_t)g * 1024 * 64;
  const __bf16* qg = qb + gbase;
  const __bf16* kg = kb + gbase;
  const __bf16* vg = vb + gbase;
  const float* qmrow = qm + (size_t)(g & 7) * 1024;  // tile(mask,(H,1)) => row g%B
  const float* kmrow = km + (size_t)(g & 7) * 1024;

  for (int c = tid; c < 1024; c += 256) {       // stage Q tile (64x64)
    int row = c >> 4;
    int ko  = (c & 15) * 4;
    *(uint2*)&Qs[row * 68 + ko] = *(const uint2*)&qg[(size_t)(qt * 64 + row) * 64 + ko];
  }

  float qmv[4];
  #pragma unroll
  for (int r = 0; r < 4; ++r) qmv[r] = qmrow[qt * 64 + tq + 16 * r];

  float ctx[4][4] = {};
  float rs[4] = {};

  for (int kt = 0; kt < 8; ++kt) {
    __syncthreads();                            // prior PV done before restage
    for (int c = tid; c < 1024; c += 256) {     // stage K,V tiles (128x64 each)
      int row = c >> 3;
      int ko  = (c & 7) * 8;
      *(uint4*)&Ks[row * 64 + ko] = *(const uint4*)&kg[(size_t)(kt * 128 + row) * 64 + ko];
      *(uint4*)&Vs[row * 64 + ko] = *(const uint4*)&vg[(size_t)(kt * 128 + row) * 64 + ko];
    }
    __syncthreads();

    float s[4][8] = {};
    for (int c2 = 0; c2 < 32; ++c2) {           // 2 channels per step
      float2 qv[4];
      #pragma unroll
      for (int r = 0; r < 4; ++r) qv[r] = bfpair(&Qs[(tq + 16 * r) * 68 + c2 * 2]);
      #pragma unroll
      for (int j = 0; j < 8; ++j) {
        float2 kv = bfpair(&Ks[(tk * 8 + j) * 64 + c2 * 2]);
        #pragma unroll
        for (int r = 0; r < 4; ++r)
          s[r][j] += qv[r].x * kv.x + qv[r].y * kv.y;
      }
    }

    float kmv[8];
    #pragma unroll
    for (int j = 0; j < 8; ++j) kmv[j] = kmrow[kt * 128 + tk * 8 + j];

    #pragma unroll
    for (int r = 0; r < 4; ++r) {               // unnormalized exp, exact ref semantics
      union { __bf16 h[8]; uint4 u; } pk;
      #pragma unroll
      for (int j = 0; j < 8; ++j) {
        float e = (qmv[r] * kmv[j] == 0.0f) ? 0.0f : __expf(s[r][j] * 0.125f);
        rs[r] += e;
        pk.h[j] = (__bf16)e;
      }
      *(uint4*)&Ps[(tq + 16 * r) * 136 + tk * 8] = pk.u;
    }
    __syncthreads();

    for (int kp = 0; kp < 64; ++kp) {           // PV: 2 k-rows per step
      float2 pv[4];
      #pragma unroll
      for (int r = 0; r < 4; ++r) pv[r] = bfpair(&Ps[(tq + 16 * r) * 136 + kp * 2]);
      float2 va0 = bfpair(&Vs[(kp * 2) * 64 + tk * 4]);
      float2 va1 = bfpair(&Vs[(kp * 2) * 64 + tk * 4 + 2]);
      float2 vb0 = bfpair(&Vs[(kp * 2 + 1) * 64 + tk * 4]);
      float2 vb1 = bfpair(&Vs[(kp * 2 + 1) * 64 + tk * 4 + 2]);
      #pragma unroll
      for (int r = 0; r < 4; ++r) {
        ctx[r][0] += pv[r].x * va0.x + pv[r].y * vb0.x;
        ctx[r][1] += pv[r].x * va0.y + pv[r].y * vb0.y;
        ctx[r][2] += pv[r].x * va1.x + pv[r].y * vb1.x;
        ctx[r][3] += pv[r].x * va1.y + pv[r].y * vb1.y;
      }
    }
  }

  #pragma unroll
  for (int r = 0; r < 4; ++r) rsred[tk][tq + 16 * r] = rs[r];
  __syncthreads();
  if (tid < 64) {
    float s = 0.f;
    #pragma unroll
    for (int i = 0; i < 16; ++i) s += rsred[i][tid];
    rowsum[tid] = fmaxf(s, 2e-15f);             // clip(sum, 2e-15) per reference
  }
  __syncthreads();

  #pragma unroll
  for (int r = 0; r < 4; ++r) {
    int row = tq + 16 * r;
    float inv = 1.0f / rowsum[row];
    #pragma unroll
    for (int c = 0; c < 4; ++c)
      ctxb[gbase + (size_t)(qt * 64 + row) * 64 + tk * 4 + c] = (__bf16)(ctx[r][c] * inv);
  }
}

__global__ __launch_bounds__(256) void ln_kernel(
    const float* __restrict__ O, const float* __restrict__ resid,
    const float* __restrict__ gam, const float* __restrict__ bet,
    float* __restrict__ out)
{
  const int row = blockIdx.x;
  const int tid = threadIdx.x;
  const float* orow = O + (size_t)row * 1024;
  const float* rrow = resid + (size_t)row * 1024;
  float x[4];
  float sum = 0.f, sq = 0.f;
  #pragma unroll
  for (int j = 0; j < 4; ++j) {
    int c = tid + j * 256;
    x[j] = orow[c] + rrow[c];
    sum += x[j];
    sq  += x[j] * x[j];
  }
  #pragma unroll
  for (int off = 32; off > 0; off >>= 1) {
    sum += __shfl_down(sum, off, 64);
    sq  += __shfl_down(sq, off, 64);
  }
  __shared__ float s1[4], s2[4];
  __shared__ float mean_s, inv_s;
  if ((tid & 63) == 0) { s1[tid >> 6] = sum; s2[tid >> 6] = sq; }
  __syncthreads();
  if (tid == 0) {
    float S = s1[0] + s1[1] + s1[2] + s1[3];
    float Q = s2[0] + s2[1] + s2[2] + s2[3];
    float mean = S * (1.0f / 1024.0f);
    float var  = fmaxf(Q * (1.0f / 1024.0f) - mean * mean, 0.0f);
    mean_s = mean;
    inv_s  = rsqrtf(var + 1e-5f);
  }
  __syncthreads();
  float mean = mean_s, inv = inv_s;
  #pragma unroll
  for (int j = 0; j < 4; ++j) {
    int c = tid + j * 256;
    out[(size_t)row * 1024 + c] = (x[j] - mean) * inv * gam[c] + bet[c];
  }
}

extern "C" void kernel_launch(void* const* d_in, const int* in_sizes, int n_in,
                              void* d_out, int out_size, void* d_ws, size_t ws_size,
                              hipStream_t stream)
{
  const float* query = (const float*)d_in[0];
  const float* keyi  = (const float*)d_in[1];
  const float* value = (const float*)d_in[2];
  const float* qmask = (const float*)d_in[3];
  const float* kmask = (const float*)d_in[4];
  const float* Wq = (const float*)d_in[5];
  const float* bq = (const float*)d_in[6];
  const float* Wk = (const float*)d_in[7];
  const float* bk = (const float*)d_in[8];
  const float* Wv = (const float*)d_in[9];
  const float* bv = (const float*)d_in[10];
  const float* Wo = (const float*)d_in[11];
  const float* bo = (const float*)d_in[12];
  const float* gam = (const float*)d_in[13];
  const float* bet = (const float*)d_in[14];

  char* ws = (char*)d_ws;                       // needs 64 MB
  __bf16* qbuf = (__bf16*)(ws);
  __bf16* kbuf = (__bf16*)(ws + ((size_t)16 << 20));
  __bf16* vbuf = (__bf16*)(ws + ((size_t)32 << 20));
  __bf16* cbuf = (__bf16*)(ws + ((size_t)48 << 20));
  float*  obuf = (float*)(ws);                  // overlays q/k slabs (dead after attn)

  dim3 gg(64, 8), tb(256);
  hipLaunchKernelGGL((gemm_bias<false, false>), gg, tb, 0, stream, (const void*)query, Wq, bq, (void*)qbuf);
  hipLaunchKernelGGL((gemm_bias<false, false>), gg, tb, 0, stream, (const void*)keyi,  Wk, bk, (void*)kbuf);
  hipLaunchKernelGGL((gemm_bias<false, false>), gg, tb, 0, stream, (const void*)value, Wv, bv, (void*)vbuf);
  hipLaunchKernelGGL(attn_kernel, dim3(16, 128), tb, 0, stream, qbuf, kbuf, vbuf, qmask, kmask, cbuf);
  hipLaunchKernelGGL((gemm_bias<true, true>), gg, tb, 0, stream, (const void*)cbuf, Wo, bo, (void*)obuf);
  hipLaunchKernelGGL(ln_kernel, dim3(8192), tb, 0, stream, obuf, query, gam, bet, (float*)d_out);
}

// Round 3
// 749.124 us; speedup vs baseline: 1.7251x; 1.7251x over previous
//
#include <hip/hip_runtime.h>
#include <hip/hip_bf16.h>

// MultiHeadAttention: B=8, L=1024, D=1024, H=16, dh=64.
// ALL inputs fp32, output fp32. Internally: bf16 MFMA GEMMs (fp32->bf16
// convert fused into LDS staging), MFMA attention (round 3), fp32 LayerNorm.
//
// Pipeline (6 launches):
//  1-3) Q/K/V = X @ W^T + b   (MFMA 128x128 tile, fp32 in -> bf16 out to ws)
//  4)   MFMA attention per head-slab g (raw-reshape: slab g = contiguous
//       [1024,64] at offset g*65536; mask row = g % B; unnormalized exp)
//  5)   O = ctx @ Wo^T + bo   (bf16 A, fp32 W -> fp32 out, overlays q/k slabs)
//  6)   LayerNorm(query + O) * gamma + beta -> d_out (fp32)
// ws: 64 MB.

typedef __bf16 bf16x8 __attribute__((ext_vector_type(8)));
typedef float  f32x4  __attribute__((ext_vector_type(4)));

#define MM 8192
#define NN 1024
#define KK 1024

union BfPack4 { __bf16 h[4]; uint2 u; };
union BfPack8 { __bf16 h[8]; uint4 u; };

// C[m,n] = sum_k A[m,k]*W[n,k] + bias[n].  W always fp32 [1024,1024] row-major.
// A fp32 or bf16 (A_BF16). Both staged into LDS as bf16, MFMA 16x16x32.
template<bool A_BF16, bool OUT_F32>
__global__ __launch_bounds__(256) void gemm_bias(
    const void* __restrict__ Ap, const float* __restrict__ W,
    const float* __restrict__ bias, void* __restrict__ Cout)
{
  __shared__ alignas(16) __bf16 As[128 * 40];  // stride 40 (80B, 8B-multiple)
  __shared__ alignas(16) __bf16 Bs[128 * 40];
  const int tid = threadIdx.x;
  const int l   = tid & 63;
  const int w   = tid >> 6;
  const int wm  = (w & 1) * 64;    // wave quadrant of the 128x128 tile
  const int wn  = (w >> 1) * 64;
  const int m0  = blockIdx.x * 128;
  const int n0  = blockIdx.y * 128;
  const int lr  = l & 15;
  const int lq  = l >> 4;

  f32x4 acc[4][4] = {};

  for (int kk = 0; kk < KK; kk += 32) {
    __syncthreads();
    if (A_BF16) {
      const __bf16* A = (const __bf16*)Ap;
      #pragma unroll
      for (int c = tid; c < 512; c += 256) {   // 512 chunks of 8 bf16
        int row = c >> 2;
        int ko  = (c & 3) * 8;
        *(uint4*)&As[row * 40 + ko] = *(const uint4*)&A[(size_t)(m0 + row) * KK + kk + ko];
      }
    } else {
      const float* A = (const float*)Ap;
      #pragma unroll
      for (int c = tid; c < 1024; c += 256) {  // 1024 chunks of 4 fp32 -> 4 bf16
        int row = c >> 3;
        int ko  = (c & 7) * 4;
        float4 f = *(const float4*)&A[(size_t)(m0 + row) * KK + kk + ko];
        BfPack4 p;
        p.h[0] = (__bf16)f.x; p.h[1] = (__bf16)f.y;
        p.h[2] = (__bf16)f.z; p.h[3] = (__bf16)f.w;
        *(uint2*)&As[row * 40 + ko] = p.u;
      }
    }
    #pragma unroll
    for (int c = tid; c < 1024; c += 256) {    // W fp32 -> bf16
      int row = c >> 3;
      int ko  = (c & 7) * 4;
      float4 f = *(const float4*)&W[(size_t)(n0 + row) * KK + kk + ko];
      BfPack4 p;
      p.h[0] = (__bf16)f.x; p.h[1] = (__bf16)f.y;
      p.h[2] = (__bf16)f.z; p.h[3] = (__bf16)f.w;
      *(uint2*)&Bs[row * 40 + ko] = p.u;
    }
    __syncthreads();
    bf16x8 af[4], bf[4];
    #pragma unroll
    for (int t = 0; t < 4; ++t) {
      af[t] = *(const bf16x8*)&As[(wm + t * 16 + lr) * 40 + lq * 8];
      bf[t] = *(const bf16x8*)&Bs[(wn + t * 16 + lr) * 40 + lq * 8];
    }
    #pragma unroll
    for (int mt = 0; mt < 4; ++mt)
      #pragma unroll
      for (int nt = 0; nt < 4; ++nt)
        acc[mt][nt] = __builtin_amdgcn_mfma_f32_16x16x32_bf16(af[mt], bf[nt], acc[mt][nt], 0, 0, 0);
  }

  // C/D layout: col = lane&15, row = (lane>>4)*4 + i   [m89/m91 verified]
  #pragma unroll
  for (int mt = 0; mt < 4; ++mt)
    #pragma unroll
    for (int nt = 0; nt < 4; ++nt)
      #pragma unroll
      for (int i = 0; i < 4; ++i) {
        int gm = m0 + wm + mt * 16 + lq * 4 + i;
        int gn = n0 + wn + nt * 16 + lr;
        float v = acc[mt][nt][i] + bias[gn];
        if (OUT_F32) ((float*)Cout)[(size_t)gm * NN + gn] = v;
        else         ((__bf16*)Cout)[(size_t)gm * NN + gn] = (__bf16)v;
      }
}

// MFMA attention. Block = (q-tile of 64 rows, head-slab g), 4 waves.
// Wave w owns q-rows [16w,16w+16). Per k-tile (128 cols):
//   S = Q K^T via 16x16x32 MFMA (8 col-tiles x 2 ksteps),
//   exp in C-layout (unnormalized, reference semantics), row-sums in regs,
//   P -> wave-private LDS rows (no barrier; C-layout -> A-layout transform),
//   PV via MFMA with V^T staged in LDS (conflict-free transposed staging).
__global__ __launch_bounds__(256) void attn_kernel(
    const __bf16* __restrict__ qb, const __bf16* __restrict__ kb,
    const __bf16* __restrict__ vb, const float* __restrict__ qm,
    const float* __restrict__ km, __bf16* __restrict__ ctxb)
{
  const int g   = blockIdx.y;   // 0..127
  const int qt  = blockIdx.x;   // 0..15
  const int tid = threadIdx.x;
  const int l   = tid & 63;
  const int w   = tid >> 6;
  const int lr  = l & 15;
  const int lq  = l >> 4;

  __shared__ alignas(16) __bf16 Qs[64 * 72];    // A-frag reads: even 8/bank
  __shared__ alignas(16) __bf16 Ks[128 * 72];
  __shared__ alignas(16) __bf16 Vt[64 * 136];   // V^T: [c][j], stride 136
  __shared__ alignas(16) __bf16 Ps[64 * 136];   // P: [q][j], wave-private rows

  const size_t gbase = (size_t)g * 1024 * 64;
  const __bf16* qg = qb + gbase;
  const __bf16* kg = kb + gbase;
  const __bf16* vg = vb + gbase;
  const float* qmrow = qm + (size_t)(g & 7) * 1024;  // tile(mask,(H,1)) => row g%B
  const float* kmrow = km + (size_t)(g & 7) * 1024;

  // stage Q tile (64x64) as bf16
  #pragma unroll
  for (int s = 0; s < 2; ++s) {
    int ch = tid + 256 * s;
    int row = ch >> 3, co = (ch & 7) * 8;
    *(uint4*)&Qs[row * 72 + co] = *(const uint4*)&qg[(size_t)(qt * 64 + row) * 64 + co];
  }

  float qmv[4];
  #pragma unroll
  for (int i = 0; i < 4; ++i) qmv[i] = qmrow[qt * 64 + w * 16 + lq * 4 + i];

  __syncthreads();
  bf16x8 qa[2];   // Q A-frags, reused all k-tiles
  qa[0] = *(const bf16x8*)&Qs[(w * 16 + lr) * 72 + lq * 8];
  qa[1] = *(const bf16x8*)&Qs[(w * 16 + lr) * 72 + 32 + lq * 8];

  float rs[4] = {};
  f32x4 ctx[4] = {};

  for (int kt = 0; kt < 8; ++kt) {
    __syncthreads();                           // prior S/PV reads of Ks/Vt done
    #pragma unroll
    for (int s = 0; s < 4; ++s) {              // stage K tile (128x64), row-major
      int ch = tid + 256 * s;
      int row = ch >> 3, co = (ch & 7) * 8;
      *(uint4*)&Ks[row * 72 + co] = *(const uint4*)&kg[(size_t)(kt * 128 + row) * 64 + co];
    }
    #pragma unroll
    for (int s = 0; s < 4; ++s) {              // stage V tile transposed -> Vt[c][j]
      int ch = tid + 256 * s;
      int c0 = ch >> 7, j = ch & 127;          // lanes of a wave span 64 distinct j
      BfPack8 vv;
      vv.u = *(const uint4*)&vg[(size_t)(kt * 128 + j) * 64 + c0 * 8];
      #pragma unroll
      for (int cc = 0; cc < 8; ++cc)
        Vt[(c0 * 8 + cc) * 136 + j] = vv.h[cc];
    }
    __syncthreads();

    // S = Q K^T for this wave's 16 q-rows x 128 k-cols
    f32x4 sacc[8];
    #pragma unroll
    for (int t = 0; t < 8; ++t) {
      bf16x8 kb0 = *(const bf16x8*)&Ks[(t * 16 + lr) * 72 + lq * 8];
      bf16x8 kb1 = *(const bf16x8*)&Ks[(t * 16 + lr) * 72 + 32 + lq * 8];
      f32x4 z = {};
      z = __builtin_amdgcn_mfma_f32_16x16x32_bf16(qa[0], kb0, z, 0, 0, 0);
      sacc[t] = __builtin_amdgcn_mfma_f32_16x16x32_bf16(qa[1], kb1, z, 0, 0, 0);
    }

    // exp (unnormalized, mask-aware), accumulate row sums, P -> LDS (A-layout
    // source). Wave-private rows: no barrier between write and A-frag read.
    #pragma unroll
    for (int t = 0; t < 8; ++t) {
      float kmv = kmrow[kt * 128 + t * 16 + lr];
      #pragma unroll
      for (int i = 0; i < 4; ++i) {
        float e = (qmv[i] * kmv == 0.0f) ? 0.0f : __expf(sacc[t][i] * 0.125f);
        rs[i] += e;
        Ps[(w * 16 + lq * 4 + i) * 136 + t * 16 + lr] = (__bf16)e;
      }
    }

    // PV: ctx[q][c] += P[q][:] V[:][c]  (B-operand = V^T rows from Vt)
    #pragma unroll
    for (int ks = 0; ks < 4; ++ks) {
      bf16x8 pa = *(const bf16x8*)&Ps[(w * 16 + lr) * 136 + ks * 32 + lq * 8];
      #pragma unroll
      for (int ct = 0; ct < 4; ++ct) {
        bf16x8 vf = *(const bf16x8*)&Vt[(ct * 16 + lr) * 136 + ks * 32 + lq * 8];
        ctx[ct] = __builtin_amdgcn_mfma_f32_16x16x32_bf16(pa, vf, ctx[ct], 0, 0, 0);
      }
    }
  }

  // row sums: reduce across the 16 lanes of each quarter (rows lq*4+i)
  #pragma unroll
  for (int i = 0; i < 4; ++i) {
    float v = rs[i];
    v += __shfl_xor(v, 1);
    v += __shfl_xor(v, 2);
    v += __shfl_xor(v, 4);
    v += __shfl_xor(v, 8);
    rs[i] = 1.0f / fmaxf(v, 2e-15f);           // clip(sum, 2e-15) per reference
  }

  // ctx C-layout: row = w*16 + lq*4 + i (matches rs), col = ct*16 + lr
  #pragma unroll
  for (int ct = 0; ct < 4; ++ct)
    #pragma unroll
    for (int i = 0; i < 4; ++i) {
      int row = w * 16 + lq * 4 + i;
      ctxb[gbase + (size_t)(qt * 64 + row) * 64 + ct * 16 + lr] =
          (__bf16)(ctx[ct][i] * rs[i]);
    }
}

__global__ __launch_bounds__(256) void ln_kernel(
    const float* __restrict__ O, const float* __restrict__ resid,
    const float* __restrict__ gam, const float* __restrict__ bet,
    float* __restrict__ out)
{
  const int row = blockIdx.x;
  const int tid = threadIdx.x;
  const float* orow = O + (size_t)row * 1024;
  const float* rrow = resid + (size_t)row * 1024;
  float x[4];
  float sum = 0.f, sq = 0.f;
  #pragma unroll
  for (int j = 0; j < 4; ++j) {
    int c = tid + j * 256;
    x[j] = orow[c] + rrow[c];
    sum += x[j];
    sq  += x[j] * x[j];
  }
  #pragma unroll
  for (int off = 32; off > 0; off >>= 1) {
    sum += __shfl_down(sum, off, 64);
    sq  += __shfl_down(sq, off, 64);
  }
  __shared__ float s1[4], s2[4];
  __shared__ float mean_s, inv_s;
  if ((tid & 63) == 0) { s1[tid >> 6] = sum; s2[tid >> 6] = sq; }
  __syncthreads();
  if (tid == 0) {
    float S = s1[0] + s1[1] + s1[2] + s1[3];
    float Q = s2[0] + s2[1] + s2[2] + s2[3];
    float mean = S * (1.0f / 1024.0f);
    float var  = fmaxf(Q * (1.0f / 1024.0f) - mean * mean, 0.0f);
    mean_s = mean;
    inv_s  = rsqrtf(var + 1e-5f);
  }
  __syncthreads();
  float mean = mean_s, inv = inv_s;
  #pragma unroll
  for (int j = 0; j < 4; ++j) {
    int c = tid + j * 256;
    out[(size_t)row * 1024 + c] = (x[j] - mean) * inv * gam[c] + bet[c];
  }
}

extern "C" void kernel_launch(void* const* d_in, const int* in_sizes, int n_in,
                              void* d_out, int out_size, void* d_ws, size_t ws_size,
                              hipStream_t stream)
{
  const float* query = (const float*)d_in[0];
  const float* keyi  = (const float*)d_in[1];
  const float* value = (const float*)d_in[2];
  const float* qmask = (const float*)d_in[3];
  const float* kmask = (const float*)d_in[4];
  const float* Wq = (const float*)d_in[5];
  const float* bq = (const float*)d_in[6];
  const float* Wk = (const float*)d_in[7];
  const float* bk = (const float*)d_in[8];
  const float* Wv = (const float*)d_in[9];
  const float* bv = (const float*)d_in[10];
  const float* Wo = (const float*)d_in[11];
  const float* bo = (const float*)d_in[12];
  const float* gam = (const float*)d_in[13];
  const float* bet = (const float*)d_in[14];

  char* ws = (char*)d_ws;                       // needs 64 MB
  __bf16* qbuf = (__bf16*)(ws);
  __bf16* kbuf = (__bf16*)(ws + ((size_t)16 << 20));
  __bf16* vbuf = (__bf16*)(ws + ((size_t)32 << 20));
  __bf16* cbuf = (__bf16*)(ws + ((size_t)48 << 20));
  float*  obuf = (float*)(ws);                  // overlays q/k slabs (dead after attn)

  dim3 gg(64, 8), tb(256);
  hipLaunchKernelGGL((gemm_bias<false, false>), gg, tb, 0, stream, (const void*)query, Wq, bq, (void*)qbuf);
  hipLaunchKernelGGL((gemm_bias<false, false>), gg, tb, 0, stream, (const void*)keyi,  Wk, bk, (void*)kbuf);
  hipLaunchKernelGGL((gemm_bias<false, false>), gg, tb, 0, stream, (const void*)value, Wv, bv, (void*)vbuf);
  hipLaunchKernelGGL(attn_kernel, dim3(16, 128), tb, 0, stream, qbuf, kbuf, vbuf, qmask, kmask, cbuf);
  hipLaunchKernelGGL((gemm_bias<true, true>), gg, tb, 0, stream, (const void*)cbuf, Wo, bo, (void*)obuf);
  hipLaunchKernelGGL(ln_kernel, dim3(8192), tb, 0, stream, obuf, query, gam, bet, (float*)d_out);
}

// Round 4
// 427.500 us; speedup vs baseline: 3.0230x; 1.7523x over previous
//
#include <hip/hip_runtime.h>
#include <hip/hip_bf16.h>

// MultiHeadAttention: B=8, L=1024, D=1024, H=16, dh=64.
// ALL inputs fp32, output fp32. bf16 MFMA GEMMs (fp32->bf16 convert fused into
// staging, register-prefetch pipeline), MFMA attention, fp32 LayerNorm.
//
// Pipeline (4 launches):
//  1) fused QKV GEMM grid(64,8,3): z selects (A,W,b,C); C bf16 -> ws slabs
//  2) MFMA attention per head-slab g (raw-reshape semantics, unnormalized exp)
//  3) O = ctx @ Wo^T + bo (bf16 A, fp32 out -> overlays dead q/k slabs)
//  4) LayerNorm(query + O) * gamma + beta -> d_out (fp32)
// ws: 64 MB.

typedef __bf16 bf16x8 __attribute__((ext_vector_type(8)));
typedef float  f32x4  __attribute__((ext_vector_type(4)));

#define NN 1024
#define KK 1024

union BfPack4 { __bf16 h[4]; uint2 u; };
union BfPack8 { __bf16 h[8]; uint4 u; };

struct G3 {
  const void*  A[3];
  const float* W[3];
  const float* bias[3];
  void*        C[3];
};

// C[m,n] = sum_k A[m,k]*W[n,k] + bias[n].  W fp32 [1024,1024] row-major.
// 128x128 tile, BK=32, LDS stride 72 elems (144 B: 16B-aligned, conflict-free
// for b64 writes and b128 frag reads). Register prefetch: next tile's global
// loads issue after barrier 2 -> latency hides behind frag-read + MFMA phase.
template<bool A_BF16, bool OUT_F32>
__global__ __launch_bounds__(256) void gemm_bias(G3 args)
{
  __shared__ alignas(16) __bf16 As[128 * 72];
  __shared__ alignas(16) __bf16 Bs[128 * 72];
  const int z   = blockIdx.z;
  const float* W    = args.W[z];
  const float* bias = args.bias[z];
  const int tid = threadIdx.x;
  const int l   = tid & 63;
  const int w   = tid >> 6;
  const int wm  = (w & 1) * 64;
  const int wn  = (w >> 1) * 64;
  const int m0  = blockIdx.x * 128;
  const int n0  = blockIdx.y * 128;
  const int lr  = l & 15;
  const int lq  = l >> 4;

  float4 pw[4];
  float4 pa_f[4];
  uint4  pa_h[2];

  // prologue: prefetch tile kk=0
  if (A_BF16) {
    const __bf16* A = (const __bf16*)args.A[z];
    #pragma unroll
    for (int s = 0; s < 2; ++s) {
      int c = tid + 256 * s; int row = c >> 2, ko = (c & 3) * 8;
      pa_h[s] = *(const uint4*)&A[(size_t)(m0 + row) * KK + ko];
    }
  } else {
    const float* A = (const float*)args.A[z];
    #pragma unroll
    for (int s = 0; s < 4; ++s) {
      int c = tid + 256 * s; int row = c >> 3, ko = (c & 7) * 4;
      pa_f[s] = *(const float4*)&A[(size_t)(m0 + row) * KK + ko];
    }
  }
  #pragma unroll
  for (int s = 0; s < 4; ++s) {
    int c = tid + 256 * s; int row = c >> 3, ko = (c & 7) * 4;
    pw[s] = *(const float4*)&W[(size_t)(n0 + row) * KK + ko];
  }

  f32x4 acc[4][4] = {};

  for (int kk = 0; kk < KK; kk += 32) {
    __syncthreads();                     // prev iter's frag reads complete
    if (A_BF16) {
      #pragma unroll
      for (int s = 0; s < 2; ++s) {
        int c = tid + 256 * s; int row = c >> 2, ko = (c & 3) * 8;
        *(uint4*)&As[row * 72 + ko] = pa_h[s];
      }
    } else {
      #pragma unroll
      for (int s = 0; s < 4; ++s) {
        int c = tid + 256 * s; int row = c >> 3, ko = (c & 7) * 4;
        BfPack4 p;
        p.h[0] = (__bf16)pa_f[s].x; p.h[1] = (__bf16)pa_f[s].y;
        p.h[2] = (__bf16)pa_f[s].z; p.h[3] = (__bf16)pa_f[s].w;
        *(uint2*)&As[row * 72 + ko] = p.u;
      }
    }
    #pragma unroll
    for (int s = 0; s < 4; ++s) {
      int c = tid + 256 * s; int row = c >> 3, ko = (c & 7) * 4;
      BfPack4 p;
      p.h[0] = (__bf16)pw[s].x; p.h[1] = (__bf16)pw[s].y;
      p.h[2] = (__bf16)pw[s].z; p.h[3] = (__bf16)pw[s].w;
      *(uint2*)&Bs[row * 72 + ko] = p.u;
    }
    __syncthreads();                     // staged data visible

    if (kk + 32 < KK) {                  // prefetch next tile; latency hides
      if (A_BF16) {                      // behind frag reads + MFMAs below
        const __bf16* A = (const __bf16*)args.A[z];
        #pragma unroll
        for (int s = 0; s < 2; ++s) {
          int c = tid + 256 * s; int row = c >> 2, ko = (c & 3) * 8;
          pa_h[s] = *(const uint4*)&A[(size_t)(m0 + row) * KK + kk + 32 + ko];
        }
      } else {
        const float* A = (const float*)args.A[z];
        #pragma unroll
        for (int s = 0; s < 4; ++s) {
          int c = tid + 256 * s; int row = c >> 3, ko = (c & 7) * 4;
          pa_f[s] = *(const float4*)&A[(size_t)(m0 + row) * KK + kk + 32 + ko];
        }
      }
      #pragma unroll
      for (int s = 0; s < 4; ++s) {
        int c = tid + 256 * s; int row = c >> 3, ko = (c & 7) * 4;
        pw[s] = *(const float4*)&W[(size_t)(n0 + row) * KK + kk + 32 + ko];
      }
    }

    bf16x8 af[4], bf[4];
    #pragma unroll
    for (int t = 0; t < 4; ++t) {
      af[t] = *(const bf16x8*)&As[(wm + t * 16 + lr) * 72 + lq * 8];
      bf[t] = *(const bf16x8*)&Bs[(wn + t * 16 + lr) * 72 + lq * 8];
    }
    #pragma unroll
    for (int mt = 0; mt < 4; ++mt)
      #pragma unroll
      for (int nt = 0; nt < 4; ++nt)
        acc[mt][nt] = __builtin_amdgcn_mfma_f32_16x16x32_bf16(af[mt], bf[nt], acc[mt][nt], 0, 0, 0);
  }

  // C/D layout: col = lane&15, row = (lane>>4)*4 + i   [m89/m91 verified]
  #pragma unroll
  for (int mt = 0; mt < 4; ++mt)
    #pragma unroll
    for (int nt = 0; nt < 4; ++nt)
      #pragma unroll
      for (int i = 0; i < 4; ++i) {
        int gm = m0 + wm + mt * 16 + lq * 4 + i;
        int gn = n0 + wn + nt * 16 + lr;
        float v = acc[mt][nt][i] + bias[gn];
        if (OUT_F32) ((float*)args.C[z])[(size_t)gm * NN + gn] = v;
        else         ((__bf16*)args.C[z])[(size_t)gm * NN + gn] = (__bf16)v;
      }
}

// MFMA attention. Block = (q-tile of 64 rows, head-slab g), 4 waves.
__global__ __launch_bounds__(256) void attn_kernel(
    const __bf16* __restrict__ qb, const __bf16* __restrict__ kb,
    const __bf16* __restrict__ vb, const float* __restrict__ qm,
    const float* __restrict__ km, __bf16* __restrict__ ctxb)
{
  const int g   = blockIdx.y;   // 0..127
  const int qt  = blockIdx.x;   // 0..15
  const int tid = threadIdx.x;
  const int l   = tid & 63;
  const int w   = tid >> 6;
  const int lr  = l & 15;
  const int lq  = l >> 4;

  __shared__ alignas(16) __bf16 Qs[64 * 72];
  __shared__ alignas(16) __bf16 Ks[128 * 72];
  __shared__ alignas(16) __bf16 Vt[64 * 136];
  __shared__ alignas(16) __bf16 Ps[64 * 136];

  const size_t gbase = (size_t)g * 1024 * 64;
  const __bf16* qg = qb + gbase;
  const __bf16* kg = kb + gbase;
  const __bf16* vg = vb + gbase;
  const float* qmrow = qm + (size_t)(g & 7) * 1024;
  const float* kmrow = km + (size_t)(g & 7) * 1024;

  #pragma unroll
  for (int s = 0; s < 2; ++s) {
    int ch = tid + 256 * s;
    int row = ch >> 3, co = (ch & 7) * 8;
    *(uint4*)&Qs[row * 72 + co] = *(const uint4*)&qg[(size_t)(qt * 64 + row) * 64 + co];
  }

  float qmv[4];
  #pragma unroll
  for (int i = 0; i < 4; ++i) qmv[i] = qmrow[qt * 64 + w * 16 + lq * 4 + i];

  __syncthreads();
  bf16x8 qa[2];
  qa[0] = *(const bf16x8*)&Qs[(w * 16 + lr) * 72 + lq * 8];
  qa[1] = *(const bf16x8*)&Qs[(w * 16 + lr) * 72 + 32 + lq * 8];

  float rs[4] = {};
  f32x4 ctx[4] = {};

  for (int kt = 0; kt < 8; ++kt) {
    __syncthreads();
    #pragma unroll
    for (int s = 0; s < 4; ++s) {
      int ch = tid + 256 * s;
      int row = ch >> 3, co = (ch & 7) * 8;
      *(uint4*)&Ks[row * 72 + co] = *(const uint4*)&kg[(size_t)(kt * 128 + row) * 64 + co];
    }
    #pragma unroll
    for (int s = 0; s < 4; ++s) {
      int ch = tid + 256 * s;
      int c0 = ch >> 7, j = ch & 127;
      BfPack8 vv;
      vv.u = *(const uint4*)&vg[(size_t)(kt * 128 + j) * 64 + c0 * 8];
      #pragma unroll
      for (int cc = 0; cc < 8; ++cc)
        Vt[(c0 * 8 + cc) * 136 + j] = vv.h[cc];
    }
    __syncthreads();

    f32x4 sacc[8];
    #pragma unroll
    for (int t = 0; t < 8; ++t) {
      bf16x8 kb0 = *(const bf16x8*)&Ks[(t * 16 + lr) * 72 + lq * 8];
      bf16x8 kb1 = *(const bf16x8*)&Ks[(t * 16 + lr) * 72 + 32 + lq * 8];
      f32x4 z = {};
      z = __builtin_amdgcn_mfma_f32_16x16x32_bf16(qa[0], kb0, z, 0, 0, 0);
      sacc[t] = __builtin_amdgcn_mfma_f32_16x16x32_bf16(qa[1], kb1, z, 0, 0, 0);
    }

    #pragma unroll
    for (int t = 0; t < 8; ++t) {
      float kmv = kmrow[kt * 128 + t * 16 + lr];
      #pragma unroll
      for (int i = 0; i < 4; ++i) {
        float e = (qmv[i] * kmv == 0.0f) ? 0.0f : __expf(sacc[t][i] * 0.125f);
        rs[i] += e;
        Ps[(w * 16 + lq * 4 + i) * 136 + t * 16 + lr] = (__bf16)e;
      }
    }

    #pragma unroll
    for (int ks = 0; ks < 4; ++ks) {
      bf16x8 pa = *(const bf16x8*)&Ps[(w * 16 + lr) * 136 + ks * 32 + lq * 8];
      #pragma unroll
      for (int ct = 0; ct < 4; ++ct) {
        bf16x8 vf = *(const bf16x8*)&Vt[(ct * 16 + lr) * 136 + ks * 32 + lq * 8];
        ctx[ct] = __builtin_amdgcn_mfma_f32_16x16x32_bf16(pa, vf, ctx[ct], 0, 0, 0);
      }
    }
  }

  #pragma unroll
  for (int i = 0; i < 4; ++i) {
    float v = rs[i];
    v += __shfl_xor(v, 1);
    v += __shfl_xor(v, 2);
    v += __shfl_xor(v, 4);
    v += __shfl_xor(v, 8);
    rs[i] = 1.0f / fmaxf(v, 2e-15f);
  }

  #pragma unroll
  for (int ct = 0; ct < 4; ++ct)
    #pragma unroll
    for (int i = 0; i < 4; ++i) {
      int row = w * 16 + lq * 4 + i;
      ctxb[gbase + (size_t)(qt * 64 + row) * 64 + ct * 16 + lr] =
          (__bf16)(ctx[ct][i] * rs[i]);
    }
}

__global__ __launch_bounds__(256) void ln_kernel(
    const float* __restrict__ O, const float* __restrict__ resid,
    const float* __restrict__ gam, const float* __restrict__ bet,
    float* __restrict__ out)
{
  const int row = blockIdx.x;
  const int tid = threadIdx.x;
  const float* orow = O + (size_t)row * 1024;
  const float* rrow = resid + (size_t)row * 1024;
  float x[4];
  float sum = 0.f, sq = 0.f;
  #pragma unroll
  for (int j = 0; j < 4; ++j) {
    int c = tid + j * 256;
    x[j] = orow[c] + rrow[c];
    sum += x[j];
    sq  += x[j] * x[j];
  }
  #pragma unroll
  for (int off = 32; off > 0; off >>= 1) {
    sum += __shfl_down(sum, off, 64);
    sq  += __shfl_down(sq, off, 64);
  }
  __shared__ float s1[4], s2[4];
  __shared__ float mean_s, inv_s;
  if ((tid & 63) == 0) { s1[tid >> 6] = sum; s2[tid >> 6] = sq; }
  __syncthreads();
  if (tid == 0) {
    float S = s1[0] + s1[1] + s1[2] + s1[3];
    float Q = s2[0] + s2[1] + s2[2] + s2[3];
    float mean = S * (1.0f / 1024.0f);
    float var  = fmaxf(Q * (1.0f / 1024.0f) - mean * mean, 0.0f);
    mean_s = mean;
    inv_s  = rsqrtf(var + 1e-5f);
  }
  __syncthreads();
  float mean = mean_s, inv = inv_s;
  #pragma unroll
  for (int j = 0; j < 4; ++j) {
    int c = tid + j * 256;
    out[(size_t)row * 1024 + c] = (x[j] - mean) * inv * gam[c] + bet[c];
  }
}

extern "C" void kernel_launch(void* const* d_in, const int* in_sizes, int n_in,
                              void* d_out, int out_size, void* d_ws, size_t ws_size,
                              hipStream_t stream)
{
  const float* query = (const float*)d_in[0];
  const float* keyi  = (const float*)d_in[1];
  const float* value = (const float*)d_in[2];
  const float* qmask = (const float*)d_in[3];
  const float* kmask = (const float*)d_in[4];
  const float* Wq = (const float*)d_in[5];
  const float* bq = (const float*)d_in[6];
  const float* Wk = (const float*)d_in[7];
  const float* bk = (const float*)d_in[8];
  const float* Wv = (const float*)d_in[9];
  const float* bv = (const float*)d_in[10];
  const float* Wo = (const float*)d_in[11];
  const float* bo = (const float*)d_in[12];
  const float* gam = (const float*)d_in[13];
  const float* bet = (const float*)d_in[14];

  char* ws = (char*)d_ws;                       // needs 64 MB
  __bf16* qbuf = (__bf16*)(ws);
  __bf16* kbuf = (__bf16*)(ws + ((size_t)16 << 20));
  __bf16* vbuf = (__bf16*)(ws + ((size_t)32 << 20));
  __bf16* cbuf = (__bf16*)(ws + ((size_t)48 << 20));
  float*  obuf = (float*)(ws);                  // overlays q/k slabs (dead after attn)

  G3 qkv;
  qkv.A[0] = query; qkv.A[1] = keyi; qkv.A[2] = value;
  qkv.W[0] = Wq;    qkv.W[1] = Wk;   qkv.W[2] = Wv;
  qkv.bias[0] = bq; qkv.bias[1] = bk; qkv.bias[2] = bv;
  qkv.C[0] = qbuf;  qkv.C[1] = kbuf; qkv.C[2] = vbuf;

  G3 op;
  op.A[0] = op.A[1] = op.A[2] = cbuf;
  op.W[0] = op.W[1] = op.W[2] = Wo;
  op.bias[0] = op.bias[1] = op.bias[2] = bo;
  op.C[0] = op.C[1] = op.C[2] = obuf;

  dim3 tb(256);
  hipLaunchKernelGGL((gemm_bias<false, false>), dim3(64, 8, 3), tb, 0, stream, qkv);
  hipLaunchKernelGGL(attn_kernel, dim3(16, 128), tb, 0, stream, qbuf, kbuf, vbuf, qmask, kmask, cbuf);
  hipLaunchKernelGGL((gemm_bias<true, true>), dim3(64, 8, 1), tb, 0, stream, op);
  hipLaunchKernelGGL(ln_kernel, dim3(8192), tb, 0, stream, obuf, query, gam, bet, (float*)d_out);
}

// Round 5
// 402.932 us; speedup vs baseline: 3.2073x; 1.0610x over previous
//
#include <hip/hip_runtime.h>
#include <hip/hip_bf16.h>

// MultiHeadAttention: B=8, L=1024, D=1024, H=16, dh=64. fp32 in/out.
// Round 5: weights pre-converted to bf16 once; B-operands staged via
// global_load_lds (async, unpadded m97 layout); O-proj is full m97 structure.
//
// Pipeline (5 launches):
//  1) cvt_w: Wq,Wk,Wv,Wo fp32 -> bf16 (8 MB in ws)
//  2) gemm_qkv grid(64,8,3): A fp32 reg-prefetch+cvt, B async -> q/k/v bf16
//  3) attn grid(16,128): MFMA attention; ctx written IN-PLACE over qbuf
//     (block (qt,g) reads exactly the q-rows it writes, staged before write)
//  4) gemm_out grid(64,8): pure m97 (A=ctx bf16 async, B=Wo bf16 async) -> fp32
//  5) ln: LayerNorm(query + O) -> d_out
// ws: qbuf/cbuf[0,16M) kbuf[16,32M) vbuf[32,48M) W4[48,56M) obuf[16,48M). 56 MB.

typedef __bf16 bf16x8 __attribute__((ext_vector_type(8)));
typedef float  f32x4  __attribute__((ext_vector_type(4)));

#define KK 1024
#define NN 1024

union BfPack4 { __bf16 h[4]; uint2 u; };
union BfPack8 { __bf16 h[8]; uint4 u; };

// async global->LDS, 16 B per lane. LDS dest = wave-uniform base + lane*16
// (m104/m108). AS3 value = low 32 bits of generic LDS address.
__device__ __forceinline__ void lds_copy16(void* lds, const void* gsrc) {
  __builtin_amdgcn_global_load_lds(
      (__attribute__((address_space(1))) void*)(uintptr_t)gsrc,
      (__attribute__((address_space(3))) void*)(unsigned int)(uintptr_t)lds,
      16, 0, 0);
}

struct Cvt4 { const float* src[4]; __bf16* dst; };

__global__ __launch_bounds__(256) void cvt_w(Cvt4 a) {
  const int z = blockIdx.y;
  const float* s = a.src[z];
  __bf16* d = a.dst + (size_t)z * (KK * NN);
  const int i = (blockIdx.x * 256 + threadIdx.x) * 4;   // grid.x*256*4 == 1M exactly
  float4 f = *(const float4*)&s[i];
  BfPack4 p;
  p.h[0] = (__bf16)f.x; p.h[1] = (__bf16)f.y;
  p.h[2] = (__bf16)f.z; p.h[3] = (__bf16)f.w;
  *(uint2*)&d[i] = p.u;
}

struct GQKV {
  const float*  A[3];
  const __bf16* W;          // z*1M elems apart
  const float*  bias[3];
  __bf16*       C[3];
};

// C[m,n] = sum_k A[m,k]*W[n,k] + bias[n]; A fp32 (reg prefetch + cvt,
// LDS stride 40), W bf16 (global_load_lds, unpadded stride 32 = m97 layout).
__global__ __launch_bounds__(256) void gemm_qkv(GQKV args)
{
  __shared__ alignas(16) __bf16 As[128 * 40];
  __shared__ alignas(16) __bf16 Bs[128 * 32];
  const int z = blockIdx.z;
  const float*  A  = args.A[z];
  const __bf16* W  = args.W + (size_t)z * KK * NN;
  const float*  bias = args.bias[z];
  __bf16* C = args.C[z];
  const int tid = threadIdx.x, l = tid & 63, w = tid >> 6;
  const int m0 = blockIdx.x * 128, n0 = blockIdx.y * 128;
  const int lr = l & 15, lq = l >> 4;
  const int wm = (w & 1) * 64, wn = (w >> 1) * 64;

  // B async: chunk c (c=tid and tid+256) = row c>>2, ko (c&3)*8; dest c*16 B
  const __bf16* gw0 = &W[(size_t)(n0 + (tid >> 2)) * KK + (tid & 3) * 8];
  const __bf16* gw1 = &W[(size_t)(n0 + 64 + (tid >> 2)) * KK + (tid & 3) * 8];
  char* lB0 = (char*)Bs + w * 1024;          // wave-uniform bases
  char* lB1 = (char*)Bs + 4096 + w * 1024;

  float4 pa[4];                               // A prefetch, tile kk=0
  #pragma unroll
  for (int s = 0; s < 4; ++s) {
    int c = tid + 256 * s; int row = c >> 3, ko = (c & 7) * 4;
    pa[s] = *(const float4*)&A[(size_t)(m0 + row) * KK + ko];
  }

  f32x4 acc[4][4] = {};

  for (int kk = 0; kk < KK; kk += 32) {
    __syncthreads();                          // prev frag reads done
    #pragma unroll
    for (int s = 0; s < 4; ++s) {             // A regs -> LDS (cvt to bf16)
      int c = tid + 256 * s; int row = c >> 3, ko = (c & 7) * 4;
      BfPack4 p;
      p.h[0] = (__bf16)pa[s].x; p.h[1] = (__bf16)pa[s].y;
      p.h[2] = (__bf16)pa[s].z; p.h[3] = (__bf16)pa[s].w;
      *(uint2*)&As[row * 40 + ko] = p.u;
    }
    lds_copy16(lB0, gw0 + kk);                // B async -> Bs
    lds_copy16(lB1, gw1 + kk);
    __syncthreads();                          // drains vmcnt: As,Bs ready
    if (kk + 32 < KK) {                       // prefetch next A tile
      #pragma unroll
      for (int s = 0; s < 4; ++s) {
        int c = tid + 256 * s; int row = c >> 3, ko = (c & 7) * 4;
        pa[s] = *(const float4*)&A[(size_t)(m0 + row) * KK + kk + 32 + ko];
      }
    }
    bf16x8 af[4], bf[4];
    #pragma unroll
    for (int t = 0; t < 4; ++t) {
      af[t] = *(const bf16x8*)&As[(wm + t * 16 + lr) * 40 + lq * 8];
      bf[t] = *(const bf16x8*)&Bs[(wn + t * 16 + lr) * 32 + lq * 8];
    }
    #pragma unroll
    for (int mt = 0; mt < 4; ++mt)
      #pragma unroll
      for (int nt = 0; nt < 4; ++nt)
        acc[mt][nt] = __builtin_amdgcn_mfma_f32_16x16x32_bf16(af[mt], bf[nt], acc[mt][nt], 0, 0, 0);
  }

  #pragma unroll
  for (int mt = 0; mt < 4; ++mt)
    #pragma unroll
    for (int nt = 0; nt < 4; ++nt)
      #pragma unroll
      for (int i = 0; i < 4; ++i) {
        int gm = m0 + wm + mt * 16 + lq * 4 + i;
        int gn = n0 + wn + nt * 16 + lr;
        C[(size_t)gm * NN + gn] = (__bf16)(acc[mt][nt][i] + bias[gn]);
      }
}

struct GO { const __bf16* A; const __bf16* W; const float* bias; float* C; };

// Pure m97 structure: both operands bf16 via global_load_lds, unpadded.
__global__ __launch_bounds__(256) void gemm_out(GO args)
{
  __shared__ alignas(16) __bf16 As[128 * 32];
  __shared__ alignas(16) __bf16 Bs[128 * 32];
  const int tid = threadIdx.x, l = tid & 63, w = tid >> 6;
  const int m0 = blockIdx.x * 128, n0 = blockIdx.y * 128;
  const int lr = l & 15, lq = l >> 4;
  const int wm = (w & 1) * 64, wn = (w >> 1) * 64;

  const __bf16* ga0 = &args.A[(size_t)(m0 + (tid >> 2)) * KK + (tid & 3) * 8];
  const __bf16* ga1 = &args.A[(size_t)(m0 + 64 + (tid >> 2)) * KK + (tid & 3) * 8];
  const __bf16* gw0 = &args.W[(size_t)(n0 + (tid >> 2)) * KK + (tid & 3) * 8];
  const __bf16* gw1 = &args.W[(size_t)(n0 + 64 + (tid >> 2)) * KK + (tid & 3) * 8];
  char* lA0 = (char*)As + w * 1024;
  char* lA1 = (char*)As + 4096 + w * 1024;
  char* lB0 = (char*)Bs + w * 1024;
  char* lB1 = (char*)Bs + 4096 + w * 1024;

  f32x4 acc[4][4] = {};

  for (int kk = 0; kk < KK; kk += 32) {
    __syncthreads();
    lds_copy16(lA0, ga0 + kk);
    lds_copy16(lA1, ga1 + kk);
    lds_copy16(lB0, gw0 + kk);
    lds_copy16(lB1, gw1 + kk);
    __syncthreads();
    bf16x8 af[4], bf[4];
    #pragma unroll
    for (int t = 0; t < 4; ++t) {
      af[t] = *(const bf16x8*)&As[(wm + t * 16 + lr) * 32 + lq * 8];
      bf[t] = *(const bf16x8*)&Bs[(wn + t * 16 + lr) * 32 + lq * 8];
    }
    #pragma unroll
    for (int mt = 0; mt < 4; ++mt)
      #pragma unroll
      for (int nt = 0; nt < 4; ++nt)
        acc[mt][nt] = __builtin_amdgcn_mfma_f32_16x16x32_bf16(af[mt], bf[nt], acc[mt][nt], 0, 0, 0);
  }

  #pragma unroll
  for (int mt = 0; mt < 4; ++mt)
    #pragma unroll
    for (int nt = 0; nt < 4; ++nt)
      #pragma unroll
      for (int i = 0; i < 4; ++i) {
        int gm = m0 + wm + mt * 16 + lq * 4 + i;
        int gn = n0 + wn + nt * 16 + lr;
        args.C[(size_t)gm * NN + gn] = acc[mt][nt][i] + args.bias[gn];
      }
}

// MFMA attention (unchanged from round 4; ctx written in-place over qbuf).
__global__ __launch_bounds__(256) void attn_kernel(
    const __bf16* __restrict__ qb, const __bf16* __restrict__ kb,
    const __bf16* __restrict__ vb, const float* __restrict__ qm,
    const float* __restrict__ km, __bf16* __restrict__ ctxb)
{
  const int g   = blockIdx.y;
  const int qt  = blockIdx.x;
  const int tid = threadIdx.x;
  const int l   = tid & 63;
  const int w   = tid >> 6;
  const int lr  = l & 15;
  const int lq  = l >> 4;

  __shared__ alignas(16) __bf16 Qs[64 * 72];
  __shared__ alignas(16) __bf16 Ks[128 * 72];
  __shared__ alignas(16) __bf16 Vt[64 * 136];
  __shared__ alignas(16) __bf16 Ps[64 * 136];

  const size_t gbase = (size_t)g * 1024 * 64;
  const __bf16* qg = qb + gbase;
  const __bf16* kg = kb + gbase;
  const __bf16* vg = vb + gbase;
  const float* qmrow = qm + (size_t)(g & 7) * 1024;
  const float* kmrow = km + (size_t)(g & 7) * 1024;

  #pragma unroll
  for (int s = 0; s < 2; ++s) {
    int ch = tid + 256 * s;
    int row = ch >> 3, co = (ch & 7) * 8;
    *(uint4*)&Qs[row * 72 + co] = *(const uint4*)&qg[(size_t)(qt * 64 + row) * 64 + co];
  }

  float qmv[4];
  #pragma unroll
  for (int i = 0; i < 4; ++i) qmv[i] = qmrow[qt * 64 + w * 16 + lq * 4 + i];

  __syncthreads();
  bf16x8 qa[2];
  qa[0] = *(const bf16x8*)&Qs[(w * 16 + lr) * 72 + lq * 8];
  qa[1] = *(const bf16x8*)&Qs[(w * 16 + lr) * 72 + 32 + lq * 8];

  float rs[4] = {};
  f32x4 ctx[4] = {};

  for (int kt = 0; kt < 8; ++kt) {
    __syncthreads();
    #pragma unroll
    for (int s = 0; s < 4; ++s) {
      int ch = tid + 256 * s;
      int row = ch >> 3, co = (ch & 7) * 8;
      *(uint4*)&Ks[row * 72 + co] = *(const uint4*)&kg[(size_t)(kt * 128 + row) * 64 + co];
    }
    #pragma unroll
    for (int s = 0; s < 4; ++s) {
      int ch = tid + 256 * s;
      int c0 = ch >> 7, j = ch & 127;
      BfPack8 vv;
      vv.u = *(const uint4*)&vg[(size_t)(kt * 128 + j) * 64 + c0 * 8];
      #pragma unroll
      for (int cc = 0; cc < 8; ++cc)
        Vt[(c0 * 8 + cc) * 136 + j] = vv.h[cc];
    }
    __syncthreads();

    f32x4 sacc[8];
    #pragma unroll
    for (int t = 0; t < 8; ++t) {
      bf16x8 kb0 = *(const bf16x8*)&Ks[(t * 16 + lr) * 72 + lq * 8];
      bf16x8 kb1 = *(const bf16x8*)&Ks[(t * 16 + lr) * 72 + 32 + lq * 8];
      f32x4 z = {};
      z = __builtin_amdgcn_mfma_f32_16x16x32_bf16(qa[0], kb0, z, 0, 0, 0);
      sacc[t] = __builtin_amdgcn_mfma_f32_16x16x32_bf16(qa[1], kb1, z, 0, 0, 0);
    }

    #pragma unroll
    for (int t = 0; t < 8; ++t) {
      float kmv = kmrow[kt * 128 + t * 16 + lr];
      #pragma unroll
      for (int i = 0; i < 4; ++i) {
        float e = (qmv[i] * kmv == 0.0f) ? 0.0f : __expf(sacc[t][i] * 0.125f);
        rs[i] += e;
        Ps[(w * 16 + lq * 4 + i) * 136 + t * 16 + lr] = (__bf16)e;
      }
    }

    #pragma unroll
    for (int ks = 0; ks < 4; ++ks) {
      bf16x8 pa = *(const bf16x8*)&Ps[(w * 16 + lr) * 136 + ks * 32 + lq * 8];
      #pragma unroll
      for (int ct = 0; ct < 4; ++ct) {
        bf16x8 vf = *(const bf16x8*)&Vt[(ct * 16 + lr) * 136 + ks * 32 + lq * 8];
        ctx[ct] = __builtin_amdgcn_mfma_f32_16x16x32_bf16(pa, vf, ctx[ct], 0, 0, 0);
      }
    }
  }

  #pragma unroll
  for (int i = 0; i < 4; ++i) {
    float v = rs[i];
    v += __shfl_xor(v, 1);
    v += __shfl_xor(v, 2);
    v += __shfl_xor(v, 4);
    v += __shfl_xor(v, 8);
    rs[i] = 1.0f / fmaxf(v, 2e-15f);
  }

  #pragma unroll
  for (int ct = 0; ct < 4; ++ct)
    #pragma unroll
    for (int i = 0; i < 4; ++i) {
      int row = w * 16 + lq * 4 + i;
      ctxb[gbase + (size_t)(qt * 64 + row) * 64 + ct * 16 + lr] =
          (__bf16)(ctx[ct][i] * rs[i]);
    }
}

__global__ __launch_bounds__(256) void ln_kernel(
    const float* __restrict__ O, const float* __restrict__ resid,
    const float* __restrict__ gam, const float* __restrict__ bet,
    float* __restrict__ out)
{
  const int row = blockIdx.x;
  const int tid = threadIdx.x;
  const float* orow = O + (size_t)row * 1024;
  const float* rrow = resid + (size_t)row * 1024;
  float x[4];
  float sum = 0.f, sq = 0.f;
  #pragma unroll
  for (int j = 0; j < 4; ++j) {
    int c = tid + j * 256;
    x[j] = orow[c] + rrow[c];
    sum += x[j];
    sq  += x[j] * x[j];
  }
  #pragma unroll
  for (int off = 32; off > 0; off >>= 1) {
    sum += __shfl_down(sum, off, 64);
    sq  += __shfl_down(sq, off, 64);
  }
  __shared__ float s1[4], s2[4];
  __shared__ float mean_s, inv_s;
  if ((tid & 63) == 0) { s1[tid >> 6] = sum; s2[tid >> 6] = sq; }
  __syncthreads();
  if (tid == 0) {
    float S = s1[0] + s1[1] + s1[2] + s1[3];
    float Q = s2[0] + s2[1] + s2[2] + s2[3];
    float mean = S * (1.0f / 1024.0f);
    float var  = fmaxf(Q * (1.0f / 1024.0f) - mean * mean, 0.0f);
    mean_s = mean;
    inv_s  = rsqrtf(var + 1e-5f);
  }
  __syncthreads();
  float mean = mean_s, inv = inv_s;
  #pragma unroll
  for (int j = 0; j < 4; ++j) {
    int c = tid + j * 256;
    out[(size_t)row * 1024 + c] = (x[j] - mean) * inv * gam[c] + bet[c];
  }
}

extern "C" void kernel_launch(void* const* d_in, const int* in_sizes, int n_in,
                              void* d_out, int out_size, void* d_ws, size_t ws_size,
                              hipStream_t stream)
{
  const float* query = (const float*)d_in[0];
  const float* keyi  = (const float*)d_in[1];
  const float* value = (const float*)d_in[2];
  const float* qmask = (const float*)d_in[3];
  const float* kmask = (const float*)d_in[4];
  const float* Wq = (const float*)d_in[5];
  const float* bq = (const float*)d_in[6];
  const float* Wk = (const float*)d_in[7];
  const float* bk = (const float*)d_in[8];
  const float* Wv = (const float*)d_in[9];
  const float* bv = (const float*)d_in[10];
  const float* Wo = (const float*)d_in[11];
  const float* bo = (const float*)d_in[12];
  const float* gam = (const float*)d_in[13];
  const float* bet = (const float*)d_in[14];

  char* ws = (char*)d_ws;                       // 56 MB used
  __bf16* qbuf = (__bf16*)(ws);                 // ctx overwrites in-place
  __bf16* kbuf = (__bf16*)(ws + ((size_t)16 << 20));
  __bf16* vbuf = (__bf16*)(ws + ((size_t)32 << 20));
  __bf16* wb   = (__bf16*)(ws + ((size_t)48 << 20));  // Wq,Wk,Wv,Wo bf16
  float*  obuf = (float*)(ws + ((size_t)16 << 20));   // overlays dead k/v

  Cvt4 cv;
  cv.src[0] = Wq; cv.src[1] = Wk; cv.src[2] = Wv; cv.src[3] = Wo;
  cv.dst = wb;

  GQKV qkv;
  qkv.A[0] = query; qkv.A[1] = keyi; qkv.A[2] = value;
  qkv.W = wb;
  qkv.bias[0] = bq; qkv.bias[1] = bk; qkv.bias[2] = bv;
  qkv.C[0] = qbuf;  qkv.C[1] = kbuf; qkv.C[2] = vbuf;

  GO op;
  op.A = qbuf;                                  // ctx (in-place over qbuf)
  op.W = wb + (size_t)3 * KK * NN;              // Wo bf16
  op.bias = bo;
  op.C = obuf;

  dim3 tb(256);
  hipLaunchKernelGGL(cvt_w, dim3(1024, 4), tb, 0, stream, cv);
  hipLaunchKernelGGL(gemm_qkv, dim3(64, 8, 3), tb, 0, stream, qkv);
  hipLaunchKernelGGL(attn_kernel, dim3(16, 128), tb, 0, stream, qbuf, kbuf, vbuf, qmask, kmask, qbuf);
  hipLaunchKernelGGL(gemm_out, dim3(64, 8), tb, 0, stream, op);
  hipLaunchKernelGGL(ln_kernel, dim3(8192), tb, 0, stream, obuf, query, gam, bet, (float*)d_out);
}

// Round 6
// 402.441 us; speedup vs baseline: 3.2112x; 1.0012x over previous
//
#include <hip/hip_runtime.h>
#include <hip/hip_bf16.h>

// MultiHeadAttention: B=8, L=1024, D=1024, H=16, dh=64. fp32 in/out.
// Round 6: true async pipeline (dbuf LDS + global_load_lds issued AFTER the
// barrier -> copy latency hidden behind a full compute phase), attn v2 with
// Q-frags in registers, XOR-swizzled P, panelized K, 2x bigger q-tile.
//
// Pipeline (5 launches):
//  1) cvt_w: Wq,Wk,Wv,Wo fp32 -> bf16 (8 MB in ws)
//  2) gemm_qkv grid(64,8,3): A fp32 reg-prefetch+cvt, B async dbuf -> q/k/v
//  3) attn grid(8,128): Q-tile 128; ctx written in-place over qbuf
//  4) gemm_out grid(64,8): both operands async dbuf, ONE barrier per K-iter
//  5) ln: LayerNorm(query + O) -> d_out
// ws: qbuf[0,16M) kbuf[16,32M) vbuf[32,48M) W4[48,56M) obuf[16,48M). 56 MB.

typedef __bf16 bf16x8 __attribute__((ext_vector_type(8)));
typedef float  f32x4  __attribute__((ext_vector_type(4)));

#define KK 1024
#define NN 1024

union BfPack4 { __bf16 h[4]; uint2 u; };
union BfPack8 { __bf16 h[8]; uint4 u; };

// async global->LDS, 16 B/lane. LDS dest = wave-uniform base + lane*16.
__device__ __forceinline__ void lds_copy16(void* lds, const void* gsrc) {
  __builtin_amdgcn_global_load_lds(
      (__attribute__((address_space(1))) void*)(uintptr_t)gsrc,
      (__attribute__((address_space(3))) void*)(unsigned int)(uintptr_t)lds,
      16, 0, 0);
}

struct Cvt4 { const float* src[4]; __bf16* dst; };

__global__ __launch_bounds__(256) void cvt_w(Cvt4 a) {
  const int z = blockIdx.y;
  const float* s = a.src[z];
  __bf16* d = a.dst + (size_t)z * (KK * NN);
  const int i = (blockIdx.x * 256 + threadIdx.x) * 4;
  float4 f = *(const float4*)&s[i];
  BfPack4 p;
  p.h[0] = (__bf16)f.x; p.h[1] = (__bf16)f.y;
  p.h[2] = (__bf16)f.z; p.h[3] = (__bf16)f.w;
  *(uint2*)&d[i] = p.u;
}

struct GQKV {
  const float*  A[3];
  const __bf16* W;
  const float*  bias[3];
  __bf16*       C[3];
};

// C = A @ W^T + b. A fp32 (register prefetch + cvt, LDS stride 40),
// W bf16 (async DOUBLE-buffered: copy for tile k+1 issued after barrier-2,
// drained at the NEXT iter's barrier-1 -> a full compute phase of hiding).
__global__ __launch_bounds__(256) void gemm_qkv(GQKV args)
{
  __shared__ alignas(16) __bf16 As[128 * 40];
  __shared__ alignas(16) __bf16 Bs[2][4096];
  const int z = blockIdx.z;
  const float*  A    = args.A[z];
  const __bf16* W    = args.W + (size_t)z * KK * NN;
  const float*  bias = args.bias[z];
  __bf16* C = args.C[z];
  const int tid = threadIdx.x, l = tid & 63, w = tid >> 6;
  const int m0 = blockIdx.x * 128, n0 = blockIdx.y * 128;
  const int lr = l & 15, lq = l >> 4;
  const int wm = (w & 1) * 64, wn = (w >> 1) * 64;

  const __bf16* gw0 = &W[(size_t)(n0 + (tid >> 2)) * KK + (tid & 3) * 8];
  const __bf16* gw1 = &W[(size_t)(n0 + 64 + (tid >> 2)) * KK + (tid & 3) * 8];

  float4 pa[4];
  #pragma unroll
  for (int s = 0; s < 4; ++s) {
    int c = tid + 256 * s; int row = c >> 3, ko = (c & 7) * 4;
    pa[s] = *(const float4*)&A[(size_t)(m0 + row) * KK + ko];
  }
  lds_copy16((char*)Bs + w * 1024,        gw0);
  lds_copy16((char*)Bs + 4096 + w * 1024, gw1);

  f32x4 acc[4][4] = {};
  int ib = 0;
  for (int kk = 0; kk < KK; kk += 32) {
    __syncthreads();          // drains B(kk) copy (landed during prev compute)
    #pragma unroll
    for (int s = 0; s < 4; ++s) {
      int c = tid + 256 * s; int row = c >> 3, ko = (c & 7) * 4;
      BfPack4 p;
      p.h[0] = (__bf16)pa[s].x; p.h[1] = (__bf16)pa[s].y;
      p.h[2] = (__bf16)pa[s].z; p.h[3] = (__bf16)pa[s].w;
      *(uint2*)&As[row * 40 + ko] = p.u;
    }
    __syncthreads();          // As visible (lgkm only; vmcnt already 0)
    if (kk + 32 < KK) {       // prefetch tile k+1: hidden behind MFMAs below
      lds_copy16((char*)Bs + (ib ^ 1) * 8192 + w * 1024,        gw0 + kk + 32);
      lds_copy16((char*)Bs + (ib ^ 1) * 8192 + 4096 + w * 1024, gw1 + kk + 32);
      #pragma unroll
      for (int s = 0; s < 4; ++s) {
        int c = tid + 256 * s; int row = c >> 3, ko = (c & 7) * 4;
        pa[s] = *(const float4*)&A[(size_t)(m0 + row) * KK + kk + 32 + ko];
      }
    }
    const __bf16* Bb = (const __bf16*)((char*)Bs + ib * 8192);
    bf16x8 af[4], bf[4];
    #pragma unroll
    for (int t = 0; t < 4; ++t) {
      af[t] = *(const bf16x8*)&As[(wm + t * 16 + lr) * 40 + lq * 8];
      bf[t] = *(const bf16x8*)&Bb[(wn + t * 16 + lr) * 32 + lq * 8];
    }
    #pragma unroll
    for (int mt = 0; mt < 4; ++mt)
      #pragma unroll
      for (int nt = 0; nt < 4; ++nt)
        acc[mt][nt] = __builtin_amdgcn_mfma_f32_16x16x32_bf16(af[mt], bf[nt], acc[mt][nt], 0, 0, 0);
    ib ^= 1;
  }

  #pragma unroll
  for (int mt = 0; mt < 4; ++mt)
    #pragma unroll
    for (int nt = 0; nt < 4; ++nt)
      #pragma unroll
      for (int i = 0; i < 4; ++i) {
        int gm = m0 + wm + mt * 16 + lq * 4 + i;
        int gn = n0 + wn + nt * 16 + lr;
        C[(size_t)gm * NN + gn] = (__bf16)(acc[mt][nt][i] + bias[gn]);
      }
}

struct GO { const __bf16* A; const __bf16* W; const float* bias; float* C; };

// Both operands bf16 async + double-buffered: ONE barrier per K-iter.
__global__ __launch_bounds__(256) void gemm_out(GO args)
{
  __shared__ alignas(16) __bf16 As[2][4096];
  __shared__ alignas(16) __bf16 Bs[2][4096];
  const int tid = threadIdx.x, l = tid & 63, w = tid >> 6;
  const int m0 = blockIdx.x * 128, n0 = blockIdx.y * 128;
  const int lr = l & 15, lq = l >> 4;
  const int wm = (w & 1) * 64, wn = (w >> 1) * 64;

  const __bf16* ga0 = &args.A[(size_t)(m0 + (tid >> 2)) * KK + (tid & 3) * 8];
  const __bf16* ga1 = &args.A[(size_t)(m0 + 64 + (tid >> 2)) * KK + (tid & 3) * 8];
  const __bf16* gw0 = &args.W[(size_t)(n0 + (tid >> 2)) * KK + (tid & 3) * 8];
  const __bf16* gw1 = &args.W[(size_t)(n0 + 64 + (tid >> 2)) * KK + (tid & 3) * 8];

  lds_copy16((char*)As + w * 1024,        ga0);
  lds_copy16((char*)As + 4096 + w * 1024, ga1);
  lds_copy16((char*)Bs + w * 1024,        gw0);
  lds_copy16((char*)Bs + 4096 + w * 1024, gw1);

  f32x4 acc[4][4] = {};
  int ib = 0;
  for (int kk = 0; kk < KK; kk += 32) {
    __syncthreads();          // drains tile-k copies (issued one iter ago)
    if (kk + 32 < KK) {       // prefetch tile k+1 into the other buffer
      lds_copy16((char*)As + (ib ^ 1) * 8192 + w * 1024,        ga0 + kk + 32);
      lds_copy16((char*)As + (ib ^ 1) * 8192 + 4096 + w * 1024, ga1 + kk + 32);
      lds_copy16((char*)Bs + (ib ^ 1) * 8192 + w * 1024,        gw0 + kk + 32);
      lds_copy16((char*)Bs + (ib ^ 1) * 8192 + 4096 + w * 1024, gw1 + kk + 32);
    }
    const __bf16* Ab = (const __bf16*)((char*)As + ib * 8192);
    const __bf16* Bb = (const __bf16*)((char*)Bs + ib * 8192);
    bf16x8 af[4], bf[4];
    #pragma unroll
    for (int t = 0; t < 4; ++t) {
      af[t] = *(const bf16x8*)&Ab[(wm + t * 16 + lr) * 32 + lq * 8];
      bf[t] = *(const bf16x8*)&Bb[(wn + t * 16 + lr) * 32 + lq * 8];
    }
    #pragma unroll
    for (int mt = 0; mt < 4; ++mt)
      #pragma unroll
      for (int nt = 0; nt < 4; ++nt)
        acc[mt][nt] = __builtin_amdgcn_mfma_f32_16x16x32_bf16(af[mt], bf[nt], acc[mt][nt], 0, 0, 0);
    ib ^= 1;
  }

  #pragma unroll
  for (int mt = 0; mt < 4; ++mt)
    #pragma unroll
    for (int nt = 0; nt < 4; ++nt)
      #pragma unroll
      for (int i = 0; i < 4; ++i) {
        int gm = m0 + wm + mt * 16 + lq * 4 + i;
        int gn = n0 + wn + nt * 16 + lr;
        args.C[(size_t)gm * NN + gn] = acc[mt][nt][i] + args.bias[gn];
      }
}

// Attention v2. Block = (q-tile 128, head-slab g); wave w owns q-rows
// [32w,32w+32). 8 K-iters of 128 j. Q async-staged into the Ps region at
// prologue, frags pinned in regs (A-reads=0 in the loop). K async into two
// stride-32 panels. V reg-prefetched, transposed via 2-way-free b16 writes.
// P round-trips LDS with XOR swizzle col^(16*((row>>3)&1)) -> conflict-free.
__global__ __launch_bounds__(256) void attn_kernel(
    const __bf16* __restrict__ qb, const __bf16* __restrict__ kb,
    const __bf16* __restrict__ vb, const float* __restrict__ qm,
    const float* __restrict__ km, __bf16* __restrict__ ctxb)
{
  const int g  = blockIdx.y;    // 0..127
  const int qt = blockIdx.x;    // 0..7
  const int tid = threadIdx.x, l = tid & 63, w = tid >> 6;
  const int lr = l & 15, lq = l >> 4;

  __shared__ alignas(16) __bf16 Ps[128 * 72];      // prologue: Q panels (16KB)
  __shared__ alignas(16) __bf16 Ks[2 * 128 * 32];  // two 32-col panels
  __shared__ alignas(16) __bf16 Vt[64 * 136];      // V^T, full 128-j tile
  __shared__ alignas(16) __bf16 kms[1024];         // k-mask gate bits

  const size_t gbase = (size_t)g * (1024 * 64);
  const __bf16* qg = qb + gbase;
  const __bf16* kg = kb + gbase;
  const __bf16* vg = vb + gbase;
  const float* qmrow = qm + (size_t)(g & 7) * 1024;
  const float* kmrow = km + (size_t)(g & 7) * 1024;

  // ---- prologue ----
  #pragma unroll
  for (int s = 0; s < 4; ++s) {               // Q 128x64 async into Ps region
    int c = tid + 256 * s;
    int p = c >> 9, r = (c >> 2) & 127, q0 = c & 3;
    lds_copy16((char*)Ps + w * 1024 + s * 4096,
               &qg[(size_t)(qt * 128 + r) * 64 + p * 32 + q0 * 8]);
  }
  {                                           // mask gate bits (nonzero-ness)
    float4 kf = *(const float4*)&kmrow[tid * 4];
    BfPack4 p;
    p.h[0] = (__bf16)(kf.x == 0.f ? 0.f : 1.f);
    p.h[1] = (__bf16)(kf.y == 0.f ? 0.f : 1.f);
    p.h[2] = (__bf16)(kf.z == 0.f ? 0.f : 1.f);
    p.h[3] = (__bf16)(kf.w == 0.f ? 0.f : 1.f);
    *(uint2*)&kms[tid * 4] = p.u;
  }
  float qmv[2][4];
  #pragma unroll
  for (int rt = 0; rt < 2; ++rt)
    #pragma unroll
    for (int i = 0; i < 4; ++i)
      qmv[rt][i] = qmrow[qt * 128 + 32 * w + rt * 16 + lq * 4 + i];

  __syncthreads();

  bf16x8 qa[2][2];                            // Q frags, pinned all 8 iters
  #pragma unroll
  for (int rt = 0; rt < 2; ++rt)
    #pragma unroll
    for (int p = 0; p < 2; ++p)
      qa[rt][p] = *(const bf16x8*)((char*)Ps + p * 8192 +
                                   (32 * w + rt * 16 + lr) * 64 + lq * 16);

  uint4 pv[4];                                // V prefetch (tile 0)
  #pragma unroll
  for (int s = 0; s < 4; ++s) {
    int ch = tid + 256 * s; int j = ch & 127, c0 = ch >> 7;
    pv[s] = *(const uint4*)&vg[(size_t)j * 64 + c0 * 8];
  }

  float rs[2][4] = {};
  f32x4 ctx[2][4] = {};

  for (int kt = 0; kt < 8; ++kt) {
    __syncthreads();                          // barrier-1
    #pragma unroll
    for (int s = 0; s < 4; ++s) {             // K async -> panels
      int c = tid + 256 * s;
      int p = c >> 9, r = (c >> 2) & 127, q0 = c & 3;
      lds_copy16((char*)Ks + w * 1024 + s * 4096,
                 &kg[(size_t)(kt * 128 + r) * 64 + p * 32 + q0 * 8]);
    }
    #pragma unroll
    for (int s = 0; s < 4; ++s) {             // V^T from prefetched regs
      int ch = tid + 256 * s; int j = ch & 127, c0 = ch >> 7;
      BfPack8 vv; vv.u = pv[s];
      #pragma unroll
      for (int cc = 0; cc < 8; ++cc)
        Vt[(c0 * 8 + cc) * 136 + j] = vv.h[cc];
    }
    __syncthreads();                          // barrier-2
    if (kt < 7) {                             // V prefetch for next tile
      #pragma unroll
      for (int s = 0; s < 4; ++s) {
        int ch = tid + 256 * s; int j = ch & 127, c0 = ch >> 7;
        pv[s] = *(const uint4*)&vg[(size_t)((kt + 1) * 128 + j) * 64 + c0 * 8];
      }
    }
    const int wkey = 16 * (lq >> 1);          // P write swizzle: row>>3 bit
    const int rkey = 16 * ((lr >> 3) & 1);    // P read swizzle: row>>3 bit
    #pragma unroll
    for (int h = 0; h < 2; ++h) {             // two 64-j halves
      f32x4 sacc[2][4];
      #pragma unroll
      for (int c4 = 0; c4 < 4; ++c4) {        // S = Q K^T
        int ct = h * 4 + c4;
        bf16x8 kb0 = *(const bf16x8*)((char*)Ks + (ct * 16 + lr) * 64 + lq * 16);
        bf16x8 kb1 = *(const bf16x8*)((char*)Ks + 8192 + (ct * 16 + lr) * 64 + lq * 16);
        #pragma unroll
        for (int rt = 0; rt < 2; ++rt) {
          f32x4 zz = {};
          zz = __builtin_amdgcn_mfma_f32_16x16x32_bf16(qa[rt][0], kb0, zz, 0, 0, 0);
          sacc[rt][c4] = __builtin_amdgcn_mfma_f32_16x16x32_bf16(qa[rt][1], kb1, zz, 0, 0, 0);
        }
      }
      #pragma unroll
      for (int c4 = 0; c4 < 4; ++c4) {        // unnormalized exp + P -> LDS
        int ct = h * 4 + c4;
        float kmv = (float)kms[kt * 128 + ct * 16 + lr];
        #pragma unroll
        for (int rt = 0; rt < 2; ++rt)
          #pragma unroll
          for (int i = 0; i < 4; ++i) {
            float e = (qmv[rt][i] * kmv == 0.f) ? 0.f
                                                : __expf(sacc[rt][c4][i] * 0.125f);
            rs[rt][i] += e;
            int row = 32 * w + rt * 16 + lq * 4 + i;
            Ps[row * 72 + ((c4 * 16 + lr) ^ wkey)] = (__bf16)e;
          }
      }
      #pragma unroll
      for (int ks = 0; ks < 2; ++ks) {        // PV for this half
        bf16x8 pa[2];
        #pragma unroll
        for (int rt = 0; rt < 2; ++rt)
          pa[rt] = *(const bf16x8*)&Ps[(32 * w + rt * 16 + lr) * 72 +
                                       ((ks * 32 + lq * 8) ^ rkey)];
        #pragma unroll
        for (int c2 = 0; c2 < 4; ++c2) {
          bf16x8 vf = *(const bf16x8*)&Vt[(c2 * 16 + lr) * 136 +
                                          h * 64 + ks * 32 + lq * 8];
          #pragma unroll
          for (int rt = 0; rt < 2; ++rt)
            ctx[rt][c2] = __builtin_amdgcn_mfma_f32_16x16x32_bf16(pa[rt], vf, ctx[rt][c2], 0, 0, 0);
        }
      }
    }
  }

  #pragma unroll
  for (int rt = 0; rt < 2; ++rt)              // row sums over 16 lr-lanes
    #pragma unroll
    for (int i = 0; i < 4; ++i) {
      float v = rs[rt][i];
      v += __shfl_xor(v, 1);
      v += __shfl_xor(v, 2);
      v += __shfl_xor(v, 4);
      v += __shfl_xor(v, 8);
      rs[rt][i] = 1.0f / fmaxf(v, 2e-15f);    // clip(sum, 2e-15) per reference
    }

  #pragma unroll
  for (int rt = 0; rt < 2; ++rt)
    #pragma unroll
    for (int c2 = 0; c2 < 4; ++c2)
      #pragma unroll
      for (int i = 0; i < 4; ++i) {
        int row = qt * 128 + 32 * w + rt * 16 + lq * 4 + i;
        ctxb[gbase + (size_t)row * 64 + c2 * 16 + lr] =
            (__bf16)(ctx[rt][c2][i] * rs[rt][i]);
      }
}

__global__ __launch_bounds__(256) void ln_kernel(
    const float* __restrict__ O, const float* __restrict__ resid,
    const float* __restrict__ gam, const float* __restrict__ bet,
    float* __restrict__ out)
{
  const int row = blockIdx.x;
  const int tid = threadIdx.x;
  const float* orow = O + (size_t)row * 1024;
  const float* rrow = resid + (size_t)row * 1024;
  float x[4];
  float sum = 0.f, sq = 0.f;
  #pragma unroll
  for (int j = 0; j < 4; ++j) {
    int c = tid + j * 256;
    x[j] = orow[c] + rrow[c];
    sum += x[j];
    sq  += x[j] * x[j];
  }
  #pragma unroll
  for (int off = 32; off > 0; off >>= 1) {
    sum += __shfl_down(sum, off, 64);
    sq  += __shfl_down(sq, off, 64);
  }
  __shared__ float s1[4], s2[4];
  __shared__ float mean_s, inv_s;
  if ((tid & 63) == 0) { s1[tid >> 6] = sum; s2[tid >> 6] = sq; }
  __syncthreads();
  if (tid == 0) {
    float S = s1[0] + s1[1] + s1[2] + s1[3];
    float Q = s2[0] + s2[1] + s2[2] + s2[3];
    float mean = S * (1.0f / 1024.0f);
    float var  = fmaxf(Q * (1.0f / 1024.0f) - mean * mean, 0.0f);
    mean_s = mean;
    inv_s  = rsqrtf(var + 1e-5f);
  }
  __syncthreads();
  float mean = mean_s, inv = inv_s;
  #pragma unroll
  for (int j = 0; j < 4; ++j) {
    int c = tid + j * 256;
    out[(size_t)row * 1024 + c] = (x[j] - mean) * inv * gam[c] + bet[c];
  }
}

extern "C" void kernel_launch(void* const* d_in, const int* in_sizes, int n_in,
                              void* d_out, int out_size, void* d_ws, size_t ws_size,
                              hipStream_t stream)
{
  const float* query = (const float*)d_in[0];
  const float* keyi  = (const float*)d_in[1];
  const float* value = (const float*)d_in[2];
  const float* qmask = (const float*)d_in[3];
  const float* kmask = (const float*)d_in[4];
  const float* Wq = (const float*)d_in[5];
  const float* bq = (const float*)d_in[6];
  const float* Wk = (const float*)d_in[7];
  const float* bk = (const float*)d_in[8];
  const float* Wv = (const float*)d_in[9];
  const float* bv = (const float*)d_in[10];
  const float* Wo = (const float*)d_in[11];
  const float* bo = (const float*)d_in[12];
  const float* gam = (const float*)d_in[13];
  const float* bet = (const float*)d_in[14];

  char* ws = (char*)d_ws;                       // 56 MB used
  __bf16* qbuf = (__bf16*)(ws);                 // ctx overwrites in-place
  __bf16* kbuf = (__bf16*)(ws + ((size_t)16 << 20));
  __bf16* vbuf = (__bf16*)(ws + ((size_t)32 << 20));
  __bf16* wb   = (__bf16*)(ws + ((size_t)48 << 20));  // Wq,Wk,Wv,Wo bf16
  float*  obuf = (float*)(ws + ((size_t)16 << 20));   // overlays dead k/v

  Cvt4 cv;
  cv.src[0] = Wq; cv.src[1] = Wk; cv.src[2] = Wv; cv.src[3] = Wo;
  cv.dst = wb;

  GQKV qkv;
  qkv.A[0] = query; qkv.A[1] = keyi; qkv.A[2] = value;
  qkv.W = wb;
  qkv.bias[0] = bq; qkv.bias[1] = bk; qkv.bias[2] = bv;
  qkv.C[0] = qbuf;  qkv.C[1] = kbuf; qkv.C[2] = vbuf;

  GO op;
  op.A = qbuf;                                  // ctx (in-place over qbuf)
  op.W = wb + (size_t)3 * KK * NN;              // Wo bf16
  op.bias = bo;
  op.C = obuf;

  dim3 tb(256);
  hipLaunchKernelGGL(cvt_w, dim3(1024, 4), tb, 0, stream, cv);
  hipLaunchKernelGGL(gemm_qkv, dim3(64, 8, 3), tb, 0, stream, qkv);
  hipLaunchKernelGGL(attn_kernel, dim3(8, 128), tb, 0, stream, qbuf, kbuf, vbuf, qmask, kmask, qbuf);
  hipLaunchKernelGGL(gemm_out, dim3(64, 8), tb, 0, stream, op);
  hipLaunchKernelGGL(ln_kernel, dim3(8192), tb, 0, stream, obuf, query, gam, bet, (float*)d_out);
}